// Round 1
// baseline (1367.306 us; speedup 1.0000x reference)
//
#include <hip/hip_runtime.h>
#include <cstddef>

#define DM 512
#define DS 64
#define L_SEQ 8192
#define NB 8
#define M_ROWS (NB * L_SEQ)      // 65536
#define LN_EPS 1e-3f
#define NCHUNK 64
#define LCH 128                  // NCHUNK * LCH == L_SEQ

// ---------------- LayerNorm: one wave (64 lanes) per row of 512 ----------------
__global__ __launch_bounds__(64) void ln_kernel(const float* __restrict__ x,
                                                const float* __restrict__ gamma,
                                                const float* __restrict__ beta,
                                                float* __restrict__ xn)
{
    size_t row = blockIdx.x;
    int lane = threadIdx.x;                       // 0..63
    const float4* xr = (const float4*)(x + row * DM);
    float4 v0 = xr[lane];
    float4 v1 = xr[lane + 64];
    float s  = v0.x + v0.y + v0.z + v0.w + v1.x + v1.y + v1.z + v1.w;
    float s2 = v0.x*v0.x + v0.y*v0.y + v0.z*v0.z + v0.w*v0.w
             + v1.x*v1.x + v1.y*v1.y + v1.z*v1.z + v1.w*v1.w;
    #pragma unroll
    for (int off = 32; off > 0; off >>= 1) {
        s  += __shfl_xor(s,  off);
        s2 += __shfl_xor(s2, off);
    }
    float mu  = s * (1.0f / DM);
    float var = s2 * (1.0f / DM) - mu * mu;
    float rs  = rsqrtf(var + LN_EPS);
    const float4* g4 = (const float4*)gamma;
    const float4* b4 = (const float4*)beta;
    float4 g0 = g4[lane],      bb0 = b4[lane];
    float4 g1 = g4[lane + 64], bb1 = b4[lane + 64];
    float4 r0, r1;
    r0.x = (v0.x - mu) * rs * g0.x + bb0.x;
    r0.y = (v0.y - mu) * rs * g0.y + bb0.y;
    r0.z = (v0.z - mu) * rs * g0.z + bb0.z;
    r0.w = (v0.w - mu) * rs * g0.w + bb0.w;
    r1.x = (v1.x - mu) * rs * g1.x + bb1.x;
    r1.y = (v1.y - mu) * rs * g1.y + bb1.y;
    r1.z = (v1.z - mu) * rs * g1.z + bb1.z;
    r1.w = (v1.w - mu) * rs * g1.w + bb1.w;
    float4* o = (float4*)(xn + row * DM);
    o[lane]      = r0;
    o[lane + 64] = r1;
}

// ---------------- Generic fp32 tiled GEMM: C = A(MxK) @ B(KxN) + epilogue ------
// epilogue: C[r][c] = acc + (bias?bias[c]:0) + (aux? (aux_scale?aux_scale[c]:1)*aux[r*N+c] : 0)
__global__ __launch_bounds__(256) void gemm_f32(const float* __restrict__ A,
                                                const float* __restrict__ Bm,
                                                const float* __restrict__ bias,
                                                const float* __restrict__ aux,
                                                const float* __restrict__ aux_scale,
                                                float* __restrict__ C,
                                                int M, int N, int K)
{
    __shared__ float As[64][16];
    __shared__ float Bs[16][64];
    const int tid = threadIdx.x;
    const int bm0 = blockIdx.x * 64;
    const int bn0 = blockIdx.y * 64;
    const int tx = tid & 15;        // 0..15  -> output cols tx*4..tx*4+3
    const int ty = tid >> 4;        // 0..15  -> output rows ty*4..ty*4+3
    const int arow = tid >> 2, aquad = tid & 3;   // A tile: 64 rows x 4 float4
    const int brow = tid >> 4, bcol4 = (tid & 15) * 4;

    float acc[4][4] = {};
    for (int k0 = 0; k0 < K; k0 += 16) {
        float4 av = *(const float4*)(A + (size_t)(bm0 + arow) * K + k0 + aquad * 4);
        float4 bv = *(const float4*)(Bm + (size_t)(k0 + brow) * N + bn0 + bcol4);
        *(float4*)&As[arow][aquad * 4] = av;
        *(float4*)&Bs[brow][bcol4]     = bv;
        __syncthreads();
        #pragma unroll
        for (int k = 0; k < 16; ++k) {
            float a0 = As[ty * 4 + 0][k];
            float a1 = As[ty * 4 + 1][k];
            float a2 = As[ty * 4 + 2][k];
            float a3 = As[ty * 4 + 3][k];
            float4 b = *(float4*)&Bs[k][tx * 4];
            acc[0][0] += a0 * b.x; acc[0][1] += a0 * b.y; acc[0][2] += a0 * b.z; acc[0][3] += a0 * b.w;
            acc[1][0] += a1 * b.x; acc[1][1] += a1 * b.y; acc[1][2] += a1 * b.z; acc[1][3] += a1 * b.w;
            acc[2][0] += a2 * b.x; acc[2][1] += a2 * b.y; acc[2][2] += a2 * b.z; acc[2][3] += a2 * b.w;
            acc[3][0] += a3 * b.x; acc[3][1] += a3 * b.y; acc[3][2] += a3 * b.z; acc[3][3] += a3 * b.w;
        }
        __syncthreads();
    }

    const int c = bn0 + tx * 4;
    float4 bia = {0, 0, 0, 0};
    if (bias) bia = *(const float4*)(bias + c);
    float4 sc = {1, 1, 1, 1};
    if (aux && aux_scale) sc = *(const float4*)(aux_scale + c);
    #pragma unroll
    for (int i = 0; i < 4; ++i) {
        int r = bm0 + ty * 4 + i;
        float4 o;
        o.x = acc[i][0] + bia.x;
        o.y = acc[i][1] + bia.y;
        o.z = acc[i][2] + bia.z;
        o.w = acc[i][3] + bia.w;
        if (aux) {
            float4 av = *(const float4*)(aux + (size_t)r * N + c);
            o.x += sc.x * av.x; o.y += sc.y * av.y; o.z += sc.z * av.z; o.w += sc.w * av.w;
        }
        *(float4*)(C + (size_t)r * N + c) = o;
    }
}

// ---------------- SSM scan (chunked, 3 passes) ----------------
__device__ inline void ssm_params(const float* A_log, const float* log_delta,
                                  const float* Bv, int n, float& Ab, float& Bb)
{
    float A  = -expf(A_log[n]);
    float dl = log1pf(expf(log_delta[n]));   // softplus
    float dA2 = dl * A * 0.5f;
    float inv = 1.0f / (1.0f - dA2);
    Ab = (1.0f + dA2) * inv;
    Bb = dl * inv * Bv[n];
}

__global__ __launch_bounds__(64) void scan_pass1(const float* __restrict__ xs,
                                                 const float* __restrict__ A_log,
                                                 const float* __restrict__ log_delta,
                                                 const float* __restrict__ Bv,
                                                 float* __restrict__ carry)
{
    int b = blockIdx.x / NCHUNK;
    int c = blockIdx.x % NCHUNK;
    int n = threadIdx.x;
    float Ab, Bb;
    ssm_params(A_log, log_delta, Bv, n, Ab, Bb);
    size_t base = ((size_t)b * L_SEQ + (size_t)c * LCH) * DS + n;
    float h = 0.0f;
    for (int t = 0; t < LCH; ++t)
        h = Ab * h + Bb * xs[base + (size_t)t * DS];
    carry[((size_t)b * NCHUNK + c) * DS + n] = h;
}

__global__ __launch_bounds__(64) void scan_pass2(const float* __restrict__ A_log,
                                                 const float* __restrict__ log_delta,
                                                 const float* __restrict__ Bv,
                                                 const float* __restrict__ carry,
                                                 float* __restrict__ hin)
{
    int b = blockIdx.x;
    int n = threadIdx.x;
    float Ab, Bb;
    ssm_params(A_log, log_delta, Bv, n, Ab, Bb);
    float powA = powf(Ab, (float)LCH);
    float h = 0.0f;
    for (int c = 0; c < NCHUNK; ++c) {
        size_t idx = ((size_t)b * NCHUNK + c) * DS + n;
        hin[idx] = h;
        h = powA * h + carry[idx];
    }
}

__global__ __launch_bounds__(64) void scan_pass3(const float* __restrict__ xs,
                                                 const float* __restrict__ A_log,
                                                 const float* __restrict__ log_delta,
                                                 const float* __restrict__ Bv,
                                                 const float* __restrict__ Cv,
                                                 const float* __restrict__ hin,
                                                 float* __restrict__ ys)
{
    int b = blockIdx.x / NCHUNK;
    int c = blockIdx.x % NCHUNK;
    int n = threadIdx.x;
    float Ab, Bb;
    ssm_params(A_log, log_delta, Bv, n, Ab, Bb);
    float Cn = Cv[n];
    size_t base = ((size_t)b * L_SEQ + (size_t)c * LCH) * DS + n;
    float h = hin[((size_t)b * NCHUNK + c) * DS + n];
    for (int t = 0; t < LCH; ++t) {
        h = Ab * h + Bb * xs[base + (size_t)t * DS];
        ys[base + (size_t)t * DS] = Cn * h;
    }
}

// ---------------- launcher ----------------
extern "C" void kernel_launch(void* const* d_in, const int* in_sizes, int n_in,
                              void* d_out, int out_size, void* d_ws, size_t ws_size,
                              hipStream_t stream)
{
    const float* x         = (const float*)d_in[0];
    const float* ln_gamma  = (const float*)d_in[1];
    const float* ln_beta   = (const float*)d_in[2];
    const float* W_in      = (const float*)d_in[3];
    const float* b_in      = (const float*)d_in[4];
    const float* W_xs      = (const float*)d_in[5];
    const float* A_log     = (const float*)d_in[6];
    const float* log_delta = (const float*)d_in[7];
    const float* Bv        = (const float*)d_in[8];
    const float* Cv        = (const float*)d_in[9];
    const float* Dv        = (const float*)d_in[10];
    const float* W_so      = (const float*)d_in[11];
    const float* W_out     = (const float*)d_in[12];
    const float* b_out     = (const float*)d_in[13];
    float* out = (float*)d_out;

    const size_t M = M_ROWS;
    float* ws = (float*)d_ws;
    float* xn    = ws;                         // M*512 floats (reused as t1 later)
    float* xs    = xn + M * (size_t)DM;        // M*64
    float* ys    = xs + M * (size_t)DS;        // M*64
    float* carry = ys + M * (size_t)DS;        // 8*64*64
    float* hin   = carry + NB * NCHUNK * DS;   // 8*64*64
    float* z     = out;                        // stash z in d_out (dead before final GEMM)
    float* t1    = xn;                         // reuse

    // 1) LayerNorm
    ln_kernel<<<dim3((unsigned)M), dim3(64), 0, stream>>>(x, ln_gamma, ln_beta, xn);
    // 2) z = xn @ W_in + b_in
    gemm_f32<<<dim3(M / 64, DM / 64), dim3(256), 0, stream>>>(xn, W_in, b_in, nullptr, nullptr, z,
                                                              (int)M, DM, DM);
    // 3) xs = z @ W_xs
    gemm_f32<<<dim3(M / 64, DS / 64), dim3(256), 0, stream>>>(z, W_xs, nullptr, nullptr, nullptr, xs,
                                                              (int)M, DS, DM);
    // 4-6) diagonal SSM scan, ys = C * h
    scan_pass1<<<dim3(NB * NCHUNK), dim3(64), 0, stream>>>(xs, A_log, log_delta, Bv, carry);
    scan_pass2<<<dim3(NB), dim3(64), 0, stream>>>(A_log, log_delta, Bv, carry, hin);
    scan_pass3<<<dim3(NB * NCHUNK), dim3(64), 0, stream>>>(xs, A_log, log_delta, Bv, Cv, hin, ys);
    // 7) t1 = ys @ W_so + D*z
    gemm_f32<<<dim3(M / 64, DM / 64), dim3(256), 0, stream>>>(ys, W_so, nullptr, z, Dv, t1,
                                                              (int)M, DM, DS);
    // 8) out = t1 @ W_out + b_out + x
    gemm_f32<<<dim3(M / 64, DM / 64), dim3(256), 0, stream>>>(t1, W_out, b_out, x, nullptr, out,
                                                              (int)M, DM, DM);
}

// Round 2
// 298.877 us; speedup vs baseline: 4.5748x; 4.5748x over previous
//
#include <hip/hip_runtime.h>
#include <hip/hip_bf16.h>
#include <cstddef>
#include <cstdint>

#define DM 512
#define DS 64
#define L_SEQ 8192
#define NB 8
#define M_ROWS (NB * L_SEQ)      // 65536
#define LN_EPS 1e-3f
#define NCHUNK 256
#define LCH 32                   // NCHUNK * LCH == L_SEQ

typedef __attribute__((ext_vector_type(8))) short short8;
typedef __attribute__((ext_vector_type(4))) short short4v;
typedef __attribute__((ext_vector_type(4))) float f32x4;
using bf16 = __hip_bfloat16;

__device__ __forceinline__ unsigned short f2bf(float f) {
    bf16 h = __float2bfloat16(f);
    return *reinterpret_cast<unsigned short*>(&h);
}

__device__ __forceinline__ void gload_lds16(const void* g, void* l) {
    __builtin_amdgcn_global_load_lds(
        (const __attribute__((address_space(1))) void*)g,
        (__attribute__((address_space(3))) void*)l, 16, 0, 0);
}

// ---------------- weight transpose + bf16 convert: WT[n][k] = bf16(W[k][n]) ----
__global__ __launch_bounds__(256) void wtrans(const float* __restrict__ W,
                                              unsigned short* __restrict__ WT,
                                              int K, int N)
{
    int i = blockIdx.x * 256 + threadIdx.x;
    if (i >= K * N) return;
    int k = i / N, n = i % N;
    WT[(size_t)n * K + k] = f2bf(W[i]);
}

// ---------------- LayerNorm: one wave per row, bf16 output ----------------
__global__ __launch_bounds__(64) void ln_kernel(const float* __restrict__ x,
                                                const float* __restrict__ gamma,
                                                const float* __restrict__ beta,
                                                unsigned short* __restrict__ xn)
{
    size_t row = blockIdx.x;
    int lane = threadIdx.x;                       // 0..63
    const float4* xr = (const float4*)(x + row * DM);
    float4 v0 = xr[lane];
    float4 v1 = xr[lane + 64];
    float s  = v0.x + v0.y + v0.z + v0.w + v1.x + v1.y + v1.z + v1.w;
    float s2 = v0.x*v0.x + v0.y*v0.y + v0.z*v0.z + v0.w*v0.w
             + v1.x*v1.x + v1.y*v1.y + v1.z*v1.z + v1.w*v1.w;
    #pragma unroll
    for (int off = 32; off > 0; off >>= 1) {
        s  += __shfl_xor(s,  off);
        s2 += __shfl_xor(s2, off);
    }
    float mu  = s * (1.0f / DM);
    float var = s2 * (1.0f / DM) - mu * mu;
    float rs  = rsqrtf(var + LN_EPS);
    const float4* g4 = (const float4*)gamma;
    const float4* b4 = (const float4*)beta;
    float4 g0 = g4[lane],      bb0 = b4[lane];
    float4 g1 = g4[lane + 64], bb1 = b4[lane + 64];
    short4v o0, o1;
    o0.x = (short)f2bf((v0.x - mu) * rs * g0.x + bb0.x);
    o0.y = (short)f2bf((v0.y - mu) * rs * g0.y + bb0.y);
    o0.z = (short)f2bf((v0.z - mu) * rs * g0.z + bb0.z);
    o0.w = (short)f2bf((v0.w - mu) * rs * g0.w + bb0.w);
    o1.x = (short)f2bf((v1.x - mu) * rs * g1.x + bb1.x);
    o1.y = (short)f2bf((v1.y - mu) * rs * g1.y + bb1.y);
    o1.z = (short)f2bf((v1.z - mu) * rs * g1.z + bb1.z);
    o1.w = (short)f2bf((v1.w - mu) * rs * g1.w + bb1.w);
    *(short4v*)(xn + row * DM + lane * 4)       = o0;
    *(short4v*)(xn + row * DM + 256 + lane * 4) = o1;
}

// ---------------- epilogue helpers ----------------
__device__ __forceinline__ float aux_to_float(float x) { return x; }
__device__ __forceinline__ float aux_to_float(bf16 x)  { return __bfloat162float(x); }
__device__ __forceinline__ void store_out(float* C, size_t i, float v) { C[i] = v; }
__device__ __forceinline__ void store_out(bf16* C, size_t i, float v)  { C[i] = __float2bfloat16(v); }

// ---------------- MFMA GEMM: C = A(MxK,bf16) @ BT^T(BT is NxK,bf16) + epilogue -
// BM=128, BK=32, 4 waves (2x2), wave tile 64 x (BN/2), 16x16x32 MFMA.
template<int BN, typename OutT, typename AuxT, bool HB, bool HA, bool HS>
__global__ __launch_bounds__(256) void gemm_mfma(const unsigned short* __restrict__ A,
                                                 const unsigned short* __restrict__ BT,
                                                 const float* __restrict__ bias,
                                                 const AuxT* __restrict__ aux,
                                                 const float* __restrict__ scale,
                                                 OutT* __restrict__ C,
                                                 int M, int N, int K)
{
    constexpr int BM = 128, BK = 32;
    constexpr int MF = 4, NF = BN / 32;
    __shared__ unsigned short As[BM * BK];
    __shared__ unsigned short Bs[BN * BK];
    const int tid  = threadIdx.x;
    const int lane = tid & 63, wid = tid >> 6;
    const int wr = wid >> 1, wc = wid & 1;          // 2x2 wave grid
    const int fr = lane & 15, fq = lane >> 4;
    const size_t bm0 = (size_t)blockIdx.x * BM;
    const int bn0 = blockIdx.y * BN;
    const int srow = lane >> 2;                     // staging row-in-seg
    const int scol = (lane & 3) * 8;                // staging col

    f32x4 acc[MF][NF];
    #pragma unroll
    for (int m = 0; m < MF; ++m)
        #pragma unroll
        for (int n = 0; n < NF; ++n)
            acc[m][n] = (f32x4){0.f, 0.f, 0.f, 0.f};

    for (int k0 = 0; k0 < K; k0 += BK) {
        #pragma unroll
        for (int j = 0; j < BM / 64; ++j) {
            int seg = j * 4 + wid;
            gload_lds16(A + (bm0 + seg * 16 + srow) * (size_t)K + k0 + scol, &As[seg * 512]);
        }
        #pragma unroll
        for (int j = 0; j < BN / 64; ++j) {
            int seg = j * 4 + wid;
            gload_lds16(BT + ((size_t)bn0 + seg * 16 + srow) * (size_t)K + k0 + scol, &Bs[seg * 512]);
        }
        __syncthreads();
        short8 af[MF], bf[NF];
        #pragma unroll
        for (int m = 0; m < MF; ++m)
            af[m] = *(const short8*)&As[(wr * 64 + m * 16 + fr) * BK + fq * 8];
        #pragma unroll
        for (int n = 0; n < NF; ++n)
            bf[n] = *(const short8*)&Bs[(wc * (BN / 2) + n * 16 + fr) * BK + fq * 8];
        #pragma unroll
        for (int m = 0; m < MF; ++m)
            #pragma unroll
            for (int n = 0; n < NF; ++n)
                acc[m][n] = __builtin_amdgcn_mfma_f32_16x16x32_bf16(af[m], bf[n], acc[m][n], 0, 0, 0);
        __syncthreads();
    }

    #pragma unroll
    for (int n = 0; n < NF; ++n) {
        int col = bn0 + wc * (BN / 2) + n * 16 + fr;
        float bv = HB ? bias[col] : 0.f;
        float sv = HS ? scale[col] : 1.f;
        #pragma unroll
        for (int m = 0; m < MF; ++m) {
            size_t row = bm0 + wr * 64 + m * 16 + fq * 4;
            #pragma unroll
            for (int r = 0; r < 4; ++r) {
                float v = acc[m][n][r] + bv;
                if (HA)
                    v += sv * aux_to_float(aux[(row + r) * (size_t)N + col]);
                store_out(C, (row + r) * (size_t)N + col, v);
            }
        }
    }
}

// ---------------- SSM scan (chunked, 3 passes) ----------------
__device__ __forceinline__ void ssm_params(const float* A_log, const float* log_delta,
                                           const float* Bv, int n, float& Ab, float& Bb)
{
    float A  = -expf(A_log[n]);
    float dl = log1pf(expf(log_delta[n]));   // softplus
    float dA2 = dl * A * 0.5f;
    float inv = 1.0f / (1.0f - dA2);
    Ab = (1.0f + dA2) * inv;
    Bb = dl * inv * Bv[n];
}

__global__ __launch_bounds__(64) void scan_pass1(const float* __restrict__ xs,
                                                 const float* __restrict__ A_log,
                                                 const float* __restrict__ log_delta,
                                                 const float* __restrict__ Bv,
                                                 float* __restrict__ carry)
{
    int b = blockIdx.x / NCHUNK;
    int c = blockIdx.x % NCHUNK;
    int n = threadIdx.x;
    float Ab, Bb;
    ssm_params(A_log, log_delta, Bv, n, Ab, Bb);
    size_t base = ((size_t)b * L_SEQ + (size_t)c * LCH) * DS + n;
    float h = 0.0f;
    for (int t = 0; t < LCH; ++t)
        h = Ab * h + Bb * xs[base + (size_t)t * DS];
    carry[((size_t)b * NCHUNK + c) * DS + n] = h;
}

__global__ __launch_bounds__(64) void scan_pass2(const float* __restrict__ A_log,
                                                 const float* __restrict__ log_delta,
                                                 const float* __restrict__ Bv,
                                                 const float* __restrict__ carry,
                                                 float* __restrict__ hin)
{
    int b = blockIdx.x;
    int n = threadIdx.x;
    float Ab, Bb;
    ssm_params(A_log, log_delta, Bv, n, Ab, Bb);
    float powA = powf(Ab, (float)LCH);
    float h = 0.0f;
    for (int c = 0; c < NCHUNK; ++c) {
        size_t idx = ((size_t)b * NCHUNK + c) * DS + n;
        hin[idx] = h;
        h = powA * h + carry[idx];
    }
}

__global__ __launch_bounds__(64) void scan_pass3(const float* __restrict__ xs,
                                                 const float* __restrict__ A_log,
                                                 const float* __restrict__ log_delta,
                                                 const float* __restrict__ Bv,
                                                 const float* __restrict__ Cv,
                                                 const float* __restrict__ hin,
                                                 unsigned short* __restrict__ ys)
{
    int b = blockIdx.x / NCHUNK;
    int c = blockIdx.x % NCHUNK;
    int n = threadIdx.x;
    float Ab, Bb;
    ssm_params(A_log, log_delta, Bv, n, Ab, Bb);
    float Cn = Cv[n];
    size_t base = ((size_t)b * L_SEQ + (size_t)c * LCH) * DS + n;
    float h = hin[((size_t)b * NCHUNK + c) * DS + n];
    for (int t = 0; t < LCH; ++t) {
        h = Ab * h + Bb * xs[base + (size_t)t * DS];
        ys[base + (size_t)t * DS] = f2bf(Cn * h);
    }
}

// ---------------- launcher ----------------
extern "C" void kernel_launch(void* const* d_in, const int* in_sizes, int n_in,
                              void* d_out, int out_size, void* d_ws, size_t ws_size,
                              hipStream_t stream)
{
    const float* x         = (const float*)d_in[0];
    const float* ln_gamma  = (const float*)d_in[1];
    const float* ln_beta   = (const float*)d_in[2];
    const float* W_in      = (const float*)d_in[3];
    const float* b_in      = (const float*)d_in[4];
    const float* W_xs      = (const float*)d_in[5];
    const float* A_log     = (const float*)d_in[6];
    const float* log_delta = (const float*)d_in[7];
    const float* Bv        = (const float*)d_in[8];
    const float* Cv        = (const float*)d_in[9];
    const float* Dv        = (const float*)d_in[10];
    const float* W_so      = (const float*)d_in[11];
    const float* W_out     = (const float*)d_in[12];
    const float* b_out     = (const float*)d_in[13];
    float* out = (float*)d_out;

    const size_t M = M_ROWS;
    // workspace layout
    float*          xs_f = (float*)d_ws;                    // M*64 f32
    unsigned short* xn_b = (unsigned short*)(xs_f + M * DS); // M*512 bf16 (aliased as t1)
    unsigned short* z_b  = xn_b + M * (size_t)DM;            // M*512 bf16
    unsigned short* ys_b = z_b + M * (size_t)DM;             // M*64 bf16
    unsigned short* WinT = ys_b + M * (size_t)DS;            // 512*512
    unsigned short* WxsT = WinT + (size_t)DM * DM;           // 64*512
    unsigned short* WsoT = WxsT + (size_t)DS * DM;           // 512*64
    unsigned short* WoutT= WsoT + (size_t)DM * DS;           // 512*512
    float* carry = (float*)(WoutT + (size_t)DM * DM);        // 8*256*64
    float* hin   = carry + NB * NCHUNK * DS;                 // 8*256*64
    unsigned short* t1_b = xn_b;                             // reuse (xn dead after G2)

    // 0) weight transpose+convert (tiny)
    wtrans<<<dim3((DM * DM + 255) / 256), dim3(256), 0, stream>>>(W_in,  WinT,  DM, DM);
    wtrans<<<dim3((DM * DS + 255) / 256), dim3(256), 0, stream>>>(W_xs,  WxsT,  DM, DS);
    wtrans<<<dim3((DS * DM + 255) / 256), dim3(256), 0, stream>>>(W_so,  WsoT,  DS, DM);
    wtrans<<<dim3((DM * DM + 255) / 256), dim3(256), 0, stream>>>(W_out, WoutT, DM, DM);
    // 1) LayerNorm -> xn (bf16)
    ln_kernel<<<dim3((unsigned)M), dim3(64), 0, stream>>>(x, ln_gamma, ln_beta, xn_b);
    // 2) z = xn @ W_in + b_in   (bf16 out)
    gemm_mfma<128, bf16, float, true, false, false>
        <<<dim3(M / 128, DM / 128), dim3(256), 0, stream>>>(xn_b, WinT, b_in, nullptr, nullptr,
                                                            (bf16*)z_b, (int)M, DM, DM);
    // 3) xs = z @ W_xs          (f32 out)
    gemm_mfma<64, float, float, false, false, false>
        <<<dim3(M / 128, 1), dim3(256), 0, stream>>>(z_b, WxsT, nullptr, nullptr, nullptr,
                                                     xs_f, (int)M, DS, DM);
    // 4-6) diagonal SSM scan, ys = C*h (bf16 out)
    scan_pass1<<<dim3(NB * NCHUNK), dim3(64), 0, stream>>>(xs_f, A_log, log_delta, Bv, carry);
    scan_pass2<<<dim3(NB), dim3(64), 0, stream>>>(A_log, log_delta, Bv, carry, hin);
    scan_pass3<<<dim3(NB * NCHUNK), dim3(64), 0, stream>>>(xs_f, A_log, log_delta, Bv, Cv, hin, ys_b);
    // 7) t1 = ys @ W_so + D*z   (bf16 out)
    gemm_mfma<128, bf16, bf16, false, true, true>
        <<<dim3(M / 128, DM / 128), dim3(256), 0, stream>>>(ys_b, WsoT, nullptr, (const bf16*)z_b,
                                                            Dv, (bf16*)t1_b, (int)M, DM, DS);
    // 8) out = t1 @ W_out + b_out + x  (f32 out)
    gemm_mfma<128, float, float, true, true, false>
        <<<dim3(M / 128, DM / 128), dim3(256), 0, stream>>>(t1_b, WoutT, b_out, x, nullptr,
                                                            out, (int)M, DM, DM);
}